// Round 3
// baseline (1347.387 us; speedup 1.0000x reference)
//
#include <hip/hip_runtime.h>
#include <cstdint>
#include <cstddef>

// ---------------- constants ----------------
#define N_TOK   16384      // 4 * 4096
#define D_TOTAL 2048
#define N_HEAD  16
#define D_HEAD  128
#define HID     512
#define MT      64         // tokens per block in fused kernel
#define RMS_EPS 1.1920929e-07f   // np.finfo(np.float32).eps

typedef __attribute__((ext_vector_type(8))) short  short8;
typedef __attribute__((ext_vector_type(4))) float  float4_t;

// ---------------- bf16 helpers (manual, RNE) ----------------
__device__ __forceinline__ unsigned short f2bf(float f) {
    union { float f; unsigned int i; } v; v.f = f;
    unsigned int b = v.i;
    b += 0x7FFFu + ((b >> 16) & 1u);      // round-to-nearest-even
    return (unsigned short)(b >> 16);
}
__device__ __forceinline__ float gelu_exact(float v) {
    return 0.5f * v * (1.0f + erff(v * 0.70710678118654752440f));
}

// ---------------- kernel 1: per-token inv-RMS (fp32 input) ----------------
__global__ __launch_bounds__(256) void rms_scale_kernel(
    const float* __restrict__ x, float* __restrict__ scale)
{
    const int token = blockIdx.x;
    const int tid   = threadIdx.x;
    const int lane  = tid & 63;
    const int wv    = tid >> 6;

    const float* xp = x + (size_t)token * D_TOTAL + tid * 8;
    float4 a = *(const float4*)(xp);
    float4 b = *(const float4*)(xp + 4);
    float s = a.x*a.x + a.y*a.y + a.z*a.z + a.w*a.w
            + b.x*b.x + b.y*b.y + b.z*b.z + b.w*b.w;

#pragma unroll
    for (int off = 32; off > 0; off >>= 1) s += __shfl_down(s, off, 64);

    __shared__ float red[4];
    if (lane == 0) red[wv] = s;
    __syncthreads();
    if (tid == 0) {
        float t = red[0] + red[1] + red[2] + red[3];
        scale[token] = rsqrtf(t * (1.0f / (float)D_TOTAL) + RMS_EPS);
    }
}

// -------- kernel 2: weight transpose+cast  W[h][K][N] (fp32) -> WT[h][N][K] (bf16)
// grid = H * (K/64) * (N/64), block = 256. LDS 64x64 tile, coalesced both ways.
__global__ __launch_bounds__(256) void transpose_kernel(
    const float* __restrict__ in, unsigned short* __restrict__ out, int K, int N)
{
    const int ktiles = K >> 6, ntiles = N >> 6;
    const int b   = blockIdx.x;
    const int h   = b / (ktiles * ntiles);
    const int rem = b % (ktiles * ntiles);
    const int kt  = rem / ntiles, nt = rem % ntiles;

    const float* src = in + (size_t)h * K * N + (size_t)(kt * 64) * N + nt * 64;
    unsigned short* dst = out + (size_t)h * N * K + (size_t)(nt * 64) * K + kt * 64;

    __shared__ unsigned short tile[64][72];   // pad to 72 (breaks pow-2 stride)

#pragma unroll
    for (int p = 0; p < 2; ++p) {
        int gi = threadIdx.x + p * 256;       // 0..511 granules of 8
        int r  = gi >> 3;                     // k-row within tile
        int gc = (gi & 7) * 8;                // col start
        float4 a  = *(const float4*)(src + (size_t)r * N + gc);
        float4 b4 = *(const float4*)(src + (size_t)r * N + gc + 4);
        unsigned short tmp[8];
        tmp[0]=f2bf(a.x);  tmp[1]=f2bf(a.y);  tmp[2]=f2bf(a.z);  tmp[3]=f2bf(a.w);
        tmp[4]=f2bf(b4.x); tmp[5]=f2bf(b4.y); tmp[6]=f2bf(b4.z); tmp[7]=f2bf(b4.w);
        *(uint4*)&tile[r][gc] = *(const uint4*)tmp;
    }
    __syncthreads();
#pragma unroll
    for (int p = 0; p < 2; ++p) {
        int gi  = threadIdx.x + p * 256;
        int r2  = gi >> 3;                    // n-row within tile
        int gc2 = (gi & 7) * 8;               // k start
        unsigned short tmp[8];
#pragma unroll
        for (int j = 0; j < 8; ++j) tmp[j] = tile[gc2 + j][r2];
        *(uint4*)(dst + (size_t)r2 * K + gc2) = *(const uint4*)tmp;
    }
}

// ---------------- fused chain GEMM stage ----------------
// out[64, N-chunk] = sAct[64, K] @ WT^T ; WT is [N][K] row-major (bf16) per head.
// MFMA 16x16x32 bf16.  A: [m=lane&15][k=quad*8+j]  B: [k=quad*8+j][n=lane&15]
template<int K, int NT>
__device__ __forceinline__ void stage_gemm(
    const unsigned short* __restrict__ sA,      // LDS, 64 rows x 512 cols, XOR-swizzled
    const unsigned short* __restrict__ wt,      // global bf16, [N][K] for this head
    int lane, int nbase, float4_t acc[4][NT])
{
#pragma unroll
    for (int mt = 0; mt < 4; ++mt)
#pragma unroll
        for (int nt = 0; nt < NT; ++nt) {
            float4_t z = {0.0f, 0.0f, 0.0f, 0.0f};
            acc[mt][nt] = z;
        }

    const int arow = lane & 15;
    const int aq   = lane >> 4;

    for (int ks = 0; ks < K / 32; ++ks) {
        short8 a[4];
        const int kg = ks * 4 + aq;           // 16B granule index along k
#pragma unroll
        for (int mt = 0; mt < 4; ++mt) {
            int m  = mt * 16 + arow;
            int g2 = kg ^ (m & 7);            // XOR swizzle (matches writes)
            a[mt] = *(const short8*)&sA[m * HID + g2 * 8];
        }
        short8 b[NT];
#pragma unroll
        for (int nt = 0; nt < NT; ++nt) {
            int n = nbase + nt * 16 + arow;
            b[nt] = *(const short8*)&wt[(size_t)n * K + ks * 32 + aq * 8];
        }
#pragma unroll
        for (int mt = 0; mt < 4; ++mt)
#pragma unroll
            for (int nt = 0; nt < NT; ++nt)
                acc[mt][nt] = __builtin_amdgcn_mfma_f32_16x16x32_bf16(
                    a[mt], b[nt], acc[mt][nt], 0, 0, 0);
    }
}

// gelu + pack + swizzled LDS writeback (C/D: col=lane&15, row=quad*4+reg)
template<int NT>
__device__ __forceinline__ void epi_gelu(
    unsigned short* __restrict__ sAct, int lane, int nbase, float4_t acc[4][NT])
{
    const int q  = lane >> 4;
    const int c0 = lane & 15;
#pragma unroll
    for (int mt = 0; mt < 4; ++mt)
#pragma unroll
        for (int nt = 0; nt < NT; ++nt)
#pragma unroll
            for (int r = 0; r < 4; ++r) {
                int row  = mt * 16 + q * 4 + r;
                int col  = nbase + nt * 16 + c0;
                float v  = gelu_exact(acc[mt][nt][r]);
                int g2   = (col >> 3) ^ (row & 7);
                sAct[row * HID + g2 * 8 + (col & 7)] = f2bf(v);
            }
}

// ---------------- kernel 3: fused per-(head, token-tile) chain ----------------
__global__ __launch_bounds__(256, 2) void fused_chain_kernel(
    const float*          __restrict__ x,     // fp32
    const float*          __restrict__ gw,    // fp32
    const float*          __restrict__ scale,
    const unsigned short* __restrict__ wt0,   // [H][512][128] bf16
    const unsigned short* __restrict__ wt1,   // [H][512][512] bf16
    const unsigned short* __restrict__ wt2,   // [H][512][512] bf16
    const unsigned short* __restrict__ wt3,   // [H][128][512] bf16
    float*                __restrict__ out)   // fp32
{
    __shared__ unsigned short sAct[MT * HID];   // 64 KiB, single buffer

    const int tid  = threadIdx.x;
    const int lane = tid & 63;
    const int wv   = tid >> 6;
    const int bx   = blockIdx.x;
    const int head = bx >> 8;            // 256 tiles per head
    const int tile = bx & 255;
    const int tok0 = tile * MT;

    // ---- stage 0: normalized x-slice (bf16) into cols [0,128) of sAct ----
#pragma unroll
    for (int p = 0; p < 4; ++p) {
        int gi = tid + p * 256;          // 0..1023 granules (64 rows x 16)
        int r  = gi >> 4;
        int gc = gi & 15;
        int token = tok0 + r;
        const float* xp = x  + (size_t)token * D_TOTAL + head * D_HEAD + gc * 8;
        const float* gp = gw + head * D_HEAD + gc * 8;
        float4 xa = *(const float4*)(xp);
        float4 xb = *(const float4*)(xp + 4);
        float4 ga = *(const float4*)(gp);
        float4 gb = *(const float4*)(gp + 4);
        float s = scale[token];
        unsigned short res[8];
        res[0]=f2bf(xa.x*s*ga.x); res[1]=f2bf(xa.y*s*ga.y);
        res[2]=f2bf(xa.z*s*ga.z); res[3]=f2bf(xa.w*s*ga.w);
        res[4]=f2bf(xb.x*s*gb.x); res[5]=f2bf(xb.y*s*gb.y);
        res[6]=f2bf(xb.z*s*gb.z); res[7]=f2bf(xb.w*s*gb.w);
        int g2 = gc ^ (r & 7);
        *(uint4*)&sAct[r * HID + g2 * 8] = *(const uint4*)res;
    }
    __syncthreads();

    float4_t acc[4][8];
    const int nb = wv * 128;             // this wave's N-chunk for stages 1-3

    // ---- stage 1: K=128 -> N=512 ----
    stage_gemm<128, 8>(sAct, wt0 + (size_t)head * HID * D_HEAD, lane, nb, acc);
    __syncthreads();                      // all reads of input region done
    epi_gelu<8>(sAct, lane, nb, acc);
    __syncthreads();

    // ---- stage 2: K=512 -> N=512 ----
    stage_gemm<512, 8>(sAct, wt1 + (size_t)head * HID * HID, lane, nb, acc);
    __syncthreads();
    epi_gelu<8>(sAct, lane, nb, acc);
    __syncthreads();

    // ---- stage 3: K=512 -> N=512 ----
    stage_gemm<512, 8>(sAct, wt2 + (size_t)head * HID * HID, lane, nb, acc);
    __syncthreads();
    epi_gelu<8>(sAct, lane, nb, acc);
    __syncthreads();

    // ---- stage 4: K=512 -> N=128, straight to global fp32 (no gelu) ----
    float4_t acc2[4][2];
    stage_gemm<512, 2>(sAct, wt3 + (size_t)head * D_HEAD * HID, lane, wv * 32, acc2);

    const int q  = lane >> 4;
    const int c0 = lane & 15;
#pragma unroll
    for (int mt = 0; mt < 4; ++mt)
#pragma unroll
        for (int nt = 0; nt < 2; ++nt)
#pragma unroll
            for (int r = 0; r < 4; ++r) {
                int row   = mt * 16 + q * 4 + r;
                int token = tok0 + row;
                int col   = head * D_HEAD + wv * 32 + nt * 16 + c0;
                out[(size_t)token * D_TOTAL + col] = acc2[mt][nt][r];
            }
}

// ---------------- host launcher ----------------
extern "C" void kernel_launch(void* const* d_in, const int* in_sizes, int n_in,
                              void* d_out, int out_size, void* d_ws, size_t ws_size,
                              hipStream_t stream)
{
    const float* x  = (const float*)d_in[0];
    const float* gw = (const float*)d_in[1];
    const float* w0 = (const float*)d_in[2];
    const float* w1 = (const float*)d_in[3];
    const float* w2 = (const float*)d_in[4];
    const float* w3 = (const float*)d_in[5];
    float* out = (float*)d_out;

    // workspace layout
    float* scale = (float*)d_ws;                                   // 64 KB
    unsigned short* wt0 = (unsigned short*)((char*)d_ws + 65536);  // [16][512][128]
    unsigned short* wt1 = wt0 + (size_t)N_HEAD * HID * D_HEAD;     // [16][512][512]
    unsigned short* wt2 = wt1 + (size_t)N_HEAD * HID * HID;        // [16][512][512]
    unsigned short* wt3 = wt2 + (size_t)N_HEAD * HID * HID;        // [16][128][512]

    rms_scale_kernel<<<N_TOK, 256, 0, stream>>>(x, scale);

    transpose_kernel<<<N_HEAD * (D_HEAD/64) * (HID/64), 256, 0, stream>>>(w0, wt0, D_HEAD, HID);
    transpose_kernel<<<N_HEAD * (HID/64)    * (HID/64), 256, 0, stream>>>(w1, wt1, HID,    HID);
    transpose_kernel<<<N_HEAD * (HID/64)    * (HID/64), 256, 0, stream>>>(w2, wt2, HID,    HID);
    transpose_kernel<<<N_HEAD * (HID/64)    * (D_HEAD/64), 256, 0, stream>>>(w3, wt3, HID, D_HEAD);

    fused_chain_kernel<<<N_HEAD * (N_TOK / MT), 256, 0, stream>>>(
        x, gw, scale, wt0, wt1, wt2, wt3, out);
}

// Round 4
// 1196.847 us; speedup vs baseline: 1.1258x; 1.1258x over previous
//
#include <hip/hip_runtime.h>
#include <cstdint>
#include <cstddef>

// ---------------- constants ----------------
#define N_TOK   16384      // 4 * 4096
#define D_TOTAL 2048
#define N_HEAD  16
#define D_HEAD  128
#define HID     512
#define MT      64         // tokens per block in fused kernel
#define RMS_EPS 1.1920929e-07f   // np.finfo(np.float32).eps

typedef __attribute__((ext_vector_type(8))) short  short8;
typedef __attribute__((ext_vector_type(4))) float  float4_t;

// ---------------- bf16 helpers (manual, RNE) ----------------
__device__ __forceinline__ unsigned short f2bf(float f) {
    union { float f; unsigned int i; } v; v.f = f;
    unsigned int b = v.i;
    b += 0x7FFFu + ((b >> 16) & 1u);      // round-to-nearest-even
    return (unsigned short)(b >> 16);
}

// Exact-GELU via Abramowitz-Stegun 7.1.26 erf (|eps| <= 1.5e-7), branchless.
// ~2x cheaper than libm erff; epilogue VALU was ~25% of busy cycles.
__device__ __forceinline__ float gelu_exact(float x) {
    float z  = x * 0.70710678118654752440f;
    float az = fabsf(z);
    float t  = __builtin_amdgcn_rcpf(fmaf(0.3275911f, az, 1.0f));
    float poly = fmaf(fmaf(fmaf(fmaf(1.061405429f, t, -1.453152027f),
                               t, 1.421413741f), t, -0.284496736f),
                      t, 0.254829592f) * t;
    float e    = exp2f(-az * az * 1.4426950408889634f);
    float erfa = fmaf(-poly, e, 1.0f);          // erf(|z|)
    float erfv = copysignf(erfa, z);
    return 0.5f * x * (1.0f + erfv);
}

// ---------------- kernel 1: per-token inv-RMS (fp32 input) ----------------
// One wave per token, no cross-wave reduction, no barriers. grid = N_TOK/4.
__global__ __launch_bounds__(256) void rms_scale_kernel(
    const float* __restrict__ x, float* __restrict__ scale)
{
    const int lane  = threadIdx.x & 63;
    const int wv    = threadIdx.x >> 6;
    const int token = blockIdx.x * 4 + wv;

    const float* xp = x + (size_t)token * D_TOTAL;
    float s = 0.0f;
#pragma unroll
    for (int j = 0; j < 8; ++j) {
        float4 v = *(const float4*)(xp + (size_t)(j * 64 + lane) * 4);
        s += v.x * v.x + v.y * v.y + v.z * v.z + v.w * v.w;
    }
#pragma unroll
    for (int off = 32; off > 0; off >>= 1) s += __shfl_down(s, off, 64);
    if (lane == 0)
        scale[token] = rsqrtf(s * (1.0f / (float)D_TOTAL) + RMS_EPS);
}

// -------- kernel 2: weight transpose+cast  W[h][K][N] (fp32) -> WT[h][N][K] (bf16)
__global__ __launch_bounds__(256) void transpose_kernel(
    const float* __restrict__ in, unsigned short* __restrict__ out, int K, int N)
{
    const int ktiles = K >> 6, ntiles = N >> 6;
    const int b   = blockIdx.x;
    const int h   = b / (ktiles * ntiles);
    const int rem = b % (ktiles * ntiles);
    const int kt  = rem / ntiles, nt = rem % ntiles;

    const float* src = in + (size_t)h * K * N + (size_t)(kt * 64) * N + nt * 64;
    unsigned short* dst = out + (size_t)h * N * K + (size_t)(nt * 64) * K + kt * 64;

    __shared__ unsigned short tile[64][72];

#pragma unroll
    for (int p = 0; p < 2; ++p) {
        int gi = threadIdx.x + p * 256;
        int r  = gi >> 3;
        int gc = (gi & 7) * 8;
        float4 a  = *(const float4*)(src + (size_t)r * N + gc);
        float4 b4 = *(const float4*)(src + (size_t)r * N + gc + 4);
        unsigned short tmp[8];
        tmp[0]=f2bf(a.x);  tmp[1]=f2bf(a.y);  tmp[2]=f2bf(a.z);  tmp[3]=f2bf(a.w);
        tmp[4]=f2bf(b4.x); tmp[5]=f2bf(b4.y); tmp[6]=f2bf(b4.z); tmp[7]=f2bf(b4.w);
        *(uint4*)&tile[r][gc] = *(const uint4*)tmp;
    }
    __syncthreads();
#pragma unroll
    for (int p = 0; p < 2; ++p) {
        int gi  = threadIdx.x + p * 256;
        int r2  = gi >> 3;
        int gc2 = (gi & 7) * 8;
        unsigned short tmp[8];
#pragma unroll
        for (int j = 0; j < 8; ++j) tmp[j] = tile[gc2 + j][r2];
        *(uint4*)(dst + (size_t)r2 * K + gc2) = *(const uint4*)tmp;
    }
}

// ---------------- fused chain GEMM stage (B software-pipelined) ----------------
// out[64, N-chunk] = sAct[64, K] @ WT^T ; WT is [N][K] row-major (bf16) per head.
// MFMA 16x16x32 bf16.  A: [m=lane&15][k=quad*8+j]  B: [k=quad*8+j][n=lane&15]
template<int K, int NT>
__device__ __forceinline__ void stage_gemm(
    const unsigned short* __restrict__ sA,      // LDS, 64 x 512, XOR-swizzled
    const unsigned short* __restrict__ wt,      // global bf16, [N][K] this head
    int lane, int nbase, float4_t acc[4][NT])
{
#pragma unroll
    for (int mt = 0; mt < 4; ++mt)
#pragma unroll
        for (int nt = 0; nt < NT; ++nt) {
            float4_t z = {0.0f, 0.0f, 0.0f, 0.0f};
            acc[mt][nt] = z;
        }

    const int arow = lane & 15;
    const int aq   = lane >> 4;

    // per-nt row base pointers (n fixed across the K loop)
    const unsigned short* brow[NT];
#pragma unroll
    for (int nt = 0; nt < NT; ++nt)
        brow[nt] = wt + (size_t)(nbase + nt * 16 + arow) * K + aq * 8;

    // prime the B pipeline (k-slice 0)
    short8 bn[NT];
#pragma unroll
    for (int nt = 0; nt < NT; ++nt) bn[nt] = *(const short8*)(brow[nt]);

    for (int ks = 0; ks < K / 32; ++ks) {
        short8 bc[NT];
#pragma unroll
        for (int nt = 0; nt < NT; ++nt) bc[nt] = bn[nt];
        if (ks + 1 < K / 32) {
#pragma unroll
            for (int nt = 0; nt < NT; ++nt)
                bn[nt] = *(const short8*)(brow[nt] + (ks + 1) * 32);
        }
        short8 a[4];
        const int kg = ks * 4 + aq;           // 16B granule index along k
#pragma unroll
        for (int mt = 0; mt < 4; ++mt) {
            int m  = mt * 16 + arow;
            int g2 = kg ^ (m & 7);            // XOR swizzle (matches writes)
            a[mt] = *(const short8*)&sA[m * HID + g2 * 8];
        }
#pragma unroll
        for (int mt = 0; mt < 4; ++mt)
#pragma unroll
            for (int nt = 0; nt < NT; ++nt)
                acc[mt][nt] = __builtin_amdgcn_mfma_f32_16x16x32_bf16(
                    a[mt], bc[nt], acc[mt][nt], 0, 0, 0);
    }
}

// gelu + pack + swizzled LDS writeback (C/D: col=lane&15, row=quad*4+reg)
template<int NT>
__device__ __forceinline__ void epi_gelu(
    unsigned short* __restrict__ sAct, int lane, int nbase, float4_t acc[4][NT])
{
    const int q  = lane >> 4;
    const int c0 = lane & 15;
#pragma unroll
    for (int mt = 0; mt < 4; ++mt)
#pragma unroll
        for (int nt = 0; nt < NT; ++nt)
#pragma unroll
            for (int r = 0; r < 4; ++r) {
                int row  = mt * 16 + q * 4 + r;
                int col  = nbase + nt * 16 + c0;
                float v  = gelu_exact(acc[mt][nt][r]);
                int g2   = (col >> 3) ^ (row & 7);
                sAct[row * HID + g2 * 8 + (col & 7)] = f2bf(v);
            }
}

// ---------------- kernel 3: fused per-(head, token-tile) chain ----------------
// XCD-aware decode: blocks land on XCD (bx & 7) [round-robin heuristic]; pin
// each XCD to 2 heads, grouped in time -> concurrent weight working set per
// XCD = 1.25 MB < 4 MB L2 (was 21 MB -> thrash to L3 = the 60% stall).
__global__ __launch_bounds__(256, 2) void fused_chain_kernel(
    const float*          __restrict__ x,     // fp32
    const float*          __restrict__ gw,    // fp32
    const float*          __restrict__ scale,
    const unsigned short* __restrict__ wt0,   // [H][512][128] bf16
    const unsigned short* __restrict__ wt1,   // [H][512][512] bf16
    const unsigned short* __restrict__ wt2,   // [H][512][512] bf16
    const unsigned short* __restrict__ wt3,   // [H][128][512] bf16
    float*                __restrict__ out)   // fp32
{
    __shared__ unsigned short sAct[MT * HID];   // 64 KiB

    const int tid  = threadIdx.x;
    const int lane = tid & 63;
    const int wv   = tid >> 6;
    const int bx    = blockIdx.x;
    const int xcd   = bx & 7;
    const int local = bx >> 3;            // 0..511
    const int head  = xcd * 2 + (local >> 8);
    const int tile  = local & 255;
    const int tok0  = tile * MT;

    // ---- stage 0: normalized x-slice (bf16) into cols [0,128) of sAct ----
#pragma unroll
    for (int p = 0; p < 4; ++p) {
        int gi = tid + p * 256;          // 0..1023 granules (64 rows x 16)
        int r  = gi >> 4;
        int gc = gi & 15;
        int token = tok0 + r;
        const float* xp = x  + (size_t)token * D_TOTAL + head * D_HEAD + gc * 8;
        const float* gp = gw + head * D_HEAD + gc * 8;
        float4 xa = *(const float4*)(xp);
        float4 xb = *(const float4*)(xp + 4);
        float4 ga = *(const float4*)(gp);
        float4 gb = *(const float4*)(gp + 4);
        float s = scale[token];
        unsigned short res[8];
        res[0]=f2bf(xa.x*s*ga.x); res[1]=f2bf(xa.y*s*ga.y);
        res[2]=f2bf(xa.z*s*ga.z); res[3]=f2bf(xa.w*s*ga.w);
        res[4]=f2bf(xb.x*s*gb.x); res[5]=f2bf(xb.y*s*gb.y);
        res[6]=f2bf(xb.z*s*gb.z); res[7]=f2bf(xb.w*s*gb.w);
        int g2 = gc ^ (r & 7);
        *(uint4*)&sAct[r * HID + g2 * 8] = *(const uint4*)res;
    }
    __syncthreads();

    float4_t acc[4][8];
    const int nb = wv * 128;             // this wave's N-chunk for stages 1-3

    // ---- stage 1: K=128 -> N=512 ----
    stage_gemm<128, 8>(sAct, wt0 + (size_t)head * HID * D_HEAD, lane, nb, acc);
    __syncthreads();
    epi_gelu<8>(sAct, lane, nb, acc);
    __syncthreads();

    // ---- stage 2: K=512 -> N=512 ----
    stage_gemm<512, 8>(sAct, wt1 + (size_t)head * HID * HID, lane, nb, acc);
    __syncthreads();
    epi_gelu<8>(sAct, lane, nb, acc);
    __syncthreads();

    // ---- stage 3: K=512 -> N=512 ----
    stage_gemm<512, 8>(sAct, wt2 + (size_t)head * HID * HID, lane, nb, acc);
    __syncthreads();
    epi_gelu<8>(sAct, lane, nb, acc);
    __syncthreads();

    // ---- stage 4: K=512 -> N=128, straight to global fp32 (no gelu) ----
    float4_t acc2[4][2];
    stage_gemm<512, 2>(sAct, wt3 + (size_t)head * D_HEAD * HID, lane, wv * 32, acc2);

    const int q  = lane >> 4;
    const int c0 = lane & 15;
#pragma unroll
    for (int mt = 0; mt < 4; ++mt)
#pragma unroll
        for (int nt = 0; nt < 2; ++nt)
#pragma unroll
            for (int r = 0; r < 4; ++r) {
                int row   = mt * 16 + q * 4 + r;
                int token = tok0 + row;
                int col   = head * D_HEAD + wv * 32 + nt * 16 + c0;
                out[(size_t)token * D_TOTAL + col] = acc2[mt][nt][r];
            }
}

// ---------------- host launcher ----------------
extern "C" void kernel_launch(void* const* d_in, const int* in_sizes, int n_in,
                              void* d_out, int out_size, void* d_ws, size_t ws_size,
                              hipStream_t stream)
{
    const float* x  = (const float*)d_in[0];
    const float* gw = (const float*)d_in[1];
    const float* w0 = (const float*)d_in[2];
    const float* w1 = (const float*)d_in[3];
    const float* w2 = (const float*)d_in[4];
    const float* w3 = (const float*)d_in[5];
    float* out = (float*)d_out;

    // workspace layout
    float* scale = (float*)d_ws;                                   // 64 KB
    unsigned short* wt0 = (unsigned short*)((char*)d_ws + 65536);  // [16][512][128]
    unsigned short* wt1 = wt0 + (size_t)N_HEAD * HID * D_HEAD;     // [16][512][512]
    unsigned short* wt2 = wt1 + (size_t)N_HEAD * HID * HID;        // [16][512][512]
    unsigned short* wt3 = wt2 + (size_t)N_HEAD * HID * HID;        // [16][128][512]

    rms_scale_kernel<<<N_TOK / 4, 256, 0, stream>>>(x, scale);

    transpose_kernel<<<N_HEAD * (D_HEAD/64) * (HID/64), 256, 0, stream>>>(w0, wt0, D_HEAD, HID);
    transpose_kernel<<<N_HEAD * (HID/64)    * (HID/64), 256, 0, stream>>>(w1, wt1, HID,    HID);
    transpose_kernel<<<N_HEAD * (HID/64)    * (HID/64), 256, 0, stream>>>(w2, wt2, HID,    HID);
    transpose_kernel<<<N_HEAD * (HID/64)    * (D_HEAD/64), 256, 0, stream>>>(w3, wt3, HID, D_HEAD);

    fused_chain_kernel<<<N_HEAD * (N_TOK / MT), 256, 0, stream>>>(
        x, gw, scale, wt0, wt1, wt2, wt3, out);
}